// Round 26
// baseline (288.787 us; speedup 1.0000x reference)
//
#include <hip/hip_runtime.h>

// PWC-Net cost volume, fp32. B=4, C=128, H=256, W=448, 81 shifts.
// out[b, di*9+dj, h, w] = (1/128) * sum_c feat1[b,c,h,w] * feat2[b,c,h+di-4,w+dj-4]
//
// R24 structure (best: 254us prof, 85% DS-engaged) minus the f1 DS traffic:
// f1 rides a 4-deep REGISTER ring in the same vmcnt FIFO as the LDS stage
// (issued at body T for body T+3; period-4 = ring-4 unroll, zero moves).
// DS instrs/block-body 42 -> 33; VMEM +8 on the near-idle TA pipe.
// (R17's f1-to-regs failed at distance-1 in one 16-wave domain; this is
// distance-3 in two 8-wave domains with counted drains.)
//
// Block = (b,h,half), 512 thr / 8 waves, 2048 blocks, 2 blocks/CU (two
// independent barrier domains). Thread owns ONE 4-px quad: it = tid ->
// di = it/56, mq = it%56 (504 active), G = half*56 + mq. acc[9][4] = 36;
// regs ~112 < cap 128 (launch_bounds(512,4)).
//
// LDS: ring-4 of channel buffers, 9 rows x 60 slots(16B) = feat2 h-4..h+4.
// Slot s = atom A0+s, A0 = half*56 (atom a = cols 4a-4..4a-1). Halo slots
// (atom 0 -> slot 0 at half=0; atom 113 -> slot 57 at half=1) zeroed once,
// never staged. Thread reads f2 slots mq..mq+2 of row di (3x ds_read_b128,
// lane-stride-16B = free 2-way).
//
// Stage = 9 wave-issues/channel (1 per f2 row, lanes 0..56):
//   half=0: dest slots 1..57 <- cols 4l ; half=1: dest slots 0..56 <- 220+4l
// OOB rows -> zws (zeros), step 0. Wave wid: j = wid (+8 if wid==0);
// nIss = wid==0 ? 2 : 1.
//
// Body T: wait vmcnt(2*(1+nIss)) [drains f1(T) + stage(T), issued 3 bodies
// (~1800cy) ago; leaves bodies T+1, T+2 in flight]; barrier; issue f1(T+3)
// -> set (T+3)&3 then stage(T+3) -> buf (T+3)&3; compute buf T&3 with f1
// set T&3. Tails 125/126/127: wait 2(1+n) / (1+n) / 0.

typedef __attribute__((ext_vector_type(4))) float f32x4;

#define GLAS(p) ((const __attribute__((address_space(1))) unsigned int*)(p))
#define LDAS(p) ((__attribute__((address_space(3))) unsigned int*)(p))

__global__ __launch_bounds__(512, 4) void cv_kernel(
    const float* __restrict__ feat1,
    const float* __restrict__ feat2,
    const float* __restrict__ zws,
    float* __restrict__ out)
{
    constexpr int C = 128, H = 256, W = 448;
    constexpr size_t HW = (size_t)H * W;
    constexpr int ROWB = 60 * 16;      // 960 B
    constexpr int BUFB = 9 * ROWB;     // 8640 B
    __shared__ __align__(16) char f2s[4 * BUFB];   // 34560 B

    const int tid  = threadIdx.x;
    const int wid  = tid >> 6;
    const int lane = tid & 63;

    // XCD-contiguous mapping (2048 = 8*256, bijective).
    const int lin  = (blockIdx.x & 7) * 256 + (blockIdx.x >> 3);
    const int half = lin & 1;
    const int bh   = lin >> 1;
    const int h    = bh & 255, b = bh >> 8;

    const int it = (tid < 504) ? tid : 503;
    const int di = it / 56;
    const int mq = it - di * 56;       // 0..55
    const int G  = half * 56 + mq;

    // Zero LDS once (halo slots persist; staged slots overwritten each use).
    for (int i = tid; i < (int)sizeof(f2s) / 16; i += 512)
        *(f32x4*)(f2s + i * 16) = (f32x4){0.f, 0.f, 0.f, 0.f};

    // Staging descriptors. Issue j = f2 row r (0..8). Lanes 0..56 load 16B:
    //   half=0: col 4*lane -> dest slot 1+lane ; half=1: col 220+4*lane -> slot lane
    const int nIss = (wid == 0) ? 2 : 1;
    const float* sp[2]; unsigned sstep[2]; int sdst[2];
#pragma unroll
    for (int k = 0; k < 2; ++k) {
        if (k < nIss) {
            const int r = wid + 8 * k;           // wid 0..7 rows 0..7; wid0/k1 row 8
            const int colf = (half ? 220 : 0) + ((lane < 57) ? lane * 4 : 0);
            const int hr = h + r - 4;
            const bool ok = (hr >= 0) && (hr < H);
            sp[k] = ok ? (feat2 + ((size_t)b * C * H + (size_t)hr) * W + colf) : zws;
            sstep[k] = ok ? (unsigned)HW : 0u;
            sdst[k] = r * ROWB + (half ? 0 : 16);
        }
    }

    // f2 read offset: slots mq..mq+2 of row di.
    const int r2o = di * ROWB + mq * 16;
    // f1: own quad (cols 4G..4G+3), register ring.
    unsigned f1o = (unsigned)(((b * C * H) + h) * W + G * 4);

    float acc[9][4];
#pragma unroll
    for (int j = 0; j < 9; ++j)
#pragma unroll
        for (int p = 0; p < 4; ++p) acc[j][p] = 0.0f;

    f32x4 f1r0, f1r1, f1r2, f1r3;

    __syncthreads();   // LDS zeros visible before first stage lands

#define F1LOAD(SET) do { \
    f1r##SET = *(const f32x4*)(feat1 + f1o); \
    f1o += (unsigned)HW; } while (0)

#define STAGE(BUFOFS) do { \
    _Pragma("unroll") \
    for (int k = 0; k < 2; ++k) { \
        if (k < nIss) { \
            if (lane < 57) \
                __builtin_amdgcn_global_load_lds(GLAS(sp[k]), \
                    LDAS(f2s + (BUFOFS) + sdst[k]), 16, 0, 0); \
            sp[k] += sstep[k]; \
        } \
    } } while (0)

// MODE 0: wait 2(1+n) + issue | 1: wait 2(1+n) | 2: wait (1+n) | 3: wait 0
#define BODY(BUF, NBUF, MODE) do { \
    if ((MODE) <= 1) { \
        if (wid == 0) asm volatile("s_waitcnt vmcnt(6)" ::: "memory"); \
        else          asm volatile("s_waitcnt vmcnt(4)" ::: "memory"); \
    } else if ((MODE) == 2) { \
        if (wid == 0) asm volatile("s_waitcnt vmcnt(3)" ::: "memory"); \
        else          asm volatile("s_waitcnt vmcnt(2)" ::: "memory"); \
    } else { \
        asm volatile("s_waitcnt vmcnt(0)" ::: "memory"); \
    } \
    __builtin_amdgcn_s_barrier(); \
    __builtin_amdgcn_sched_barrier(0); \
    if ((MODE) == 0) { F1LOAD(NBUF); STAGE((NBUF) * BUFB); } \
    { \
        const char* lb = f2s + (BUF) * BUFB; \
        const f32x4 L  = *(const f32x4*)(lb + r2o); \
        const f32x4 Cq = *(const f32x4*)(lb + r2o + 16); \
        const f32x4 R  = *(const f32x4*)(lb + r2o + 32); \
        const float w[12] = {L.x, L.y, L.z, L.w, Cq.x, Cq.y, Cq.z, Cq.w, \
                             R.x, R.y, R.z, R.w}; \
        const float a[4] = {f1r##BUF.x, f1r##BUF.y, f1r##BUF.z, f1r##BUF.w}; \
        _Pragma("unroll") \
        for (int dj = 0; dj < 9; ++dj) { \
            _Pragma("unroll") \
            for (int p = 0; p < 4; ++p) \
                acc[dj][p] = fmaf(a[p], w[dj + p], acc[dj][p]); \
        } \
    } } while (0)

    // Prologue: [f1(0),stage(0)], [f1(1),stage(1)], [f1(2),stage(2)].
    F1LOAD(0); STAGE(0 * BUFB);
    F1LOAD(1); STAGE(1 * BUFB);
    F1LOAD(2); STAGE(2 * BUFB);

    // Bodies 0..124 issue body T+3; tails 125 (2(1+n)), 126 ((1+n)), 127 (0).
#pragma unroll 1
    for (int g = 0; g < 31; ++g) {
        BODY(0, 3, 0);
        BODY(1, 0, 0);
        BODY(2, 1, 0);
        BODY(3, 2, 0);
    }
    BODY(0, 3, 0);   // T=124: issues f1(127), stage(127)
    BODY(1, 0, 1);   // T=125
    BODY(2, 1, 2);   // T=126
    BODY(3, 2, 3);   // T=127

#undef F1LOAD
#undef STAGE
#undef BODY

    if (tid < 504) {
        const float s = 1.0f / 128.0f;
        float* ob = out + (((size_t)(b * 81 + di * 9)) * H + h) * W + G * 4;
#pragma unroll
        for (int dj = 0; dj < 9; ++dj) {
            f32x4 ov = {acc[dj][0] * s, acc[dj][1] * s,
                        acc[dj][2] * s, acc[dj][3] * s};
            *(f32x4*)(ob + (size_t)dj * HW) = ov;
        }
    }
}

extern "C" void kernel_launch(void* const* d_in, const int* in_sizes, int n_in,
                              void* d_out, int out_size, void* d_ws, size_t ws_size,
                              hipStream_t stream) {
    const float* feat1 = (const float*)d_in[0];
    const float* feat2 = (const float*)d_in[1];
    float* out = (float*)d_out;
    // 1 KiB zeros: stage source for vertically-OOB feat2 rows (lane*4 floats).
    hipMemsetAsync(d_ws, 0, 1024, stream);
    cv_kernel<<<dim3(2048), dim3(512), 0, stream>>>(
        feat1, feat2, (const float*)d_ws, out);
}